// Round 5
// baseline (399.985 us; speedup 1.0000x reference)
//
#include <hip/hip_runtime.h>
#include <hip/hip_bf16.h>
#include <stdint.h>

typedef __bf16 bf16_t;
typedef __bf16 bf16x8 __attribute__((ext_vector_type(8)));
typedef float  f32x16 __attribute__((ext_vector_type(16)));

#define BM 256
#define BN 256
#define BK 32
#define NTHREADS 512

// ---------------- Kernel 1: global absmax of weight ----------------
__global__ void k_absmax(const float* __restrict__ w, unsigned int* __restrict__ out_bits, int n4) {
    int i = blockIdx.x * blockDim.x + threadIdx.x;
    int stride = gridDim.x * blockDim.x;
    const float4* w4 = (const float4*)w;
    float m = 0.0f;
    for (; i < n4; i += stride) {
        float4 v = w4[i];
        m = fmaxf(m, fmaxf(fmaxf(fabsf(v.x), fabsf(v.y)), fmaxf(fabsf(v.z), fabsf(v.w))));
    }
    #pragma unroll
    for (int off = 32; off; off >>= 1)
        m = fmaxf(m, __shfl_xor(m, off));
    if ((threadIdx.x & 63) == 0)
        atomicMax(out_bits, __float_as_uint(m));  // values >= 0: uint order == float order
}

// ---------------- e4m3fn round-to-nearest-even (positive inputs, <= 448) ----------------
__device__ __forceinline__ float e4m3_rne(float v) {
    if (v < 0.015625f) {                 // subnormal range: quantum 2^-9
        return rintf(v * 512.0f) * (1.0f / 512.0f);
    }
    unsigned int u = __float_as_uint(v);
    unsigned int keep = u >> 20;         // sign+exp+3 mantissa bits
    unsigned int r = u & 0xFFFFFu;       // 20 dropped bits
    if (r > 0x80000u || (r == 0x80000u && (keep & 1u))) keep++;
    return __uint_as_float(keep << 20);
}

// ---------------- Kernel 2: NVFP4 fake-quantize weight -> bf16 ----------------
__global__ void k_quantize(const float* __restrict__ w, bf16_t* __restrict__ wq,
                           const unsigned int* __restrict__ maxbits, int nblk) {
    int t = blockIdx.x * blockDim.x + threadIdx.x;
    if (t >= nblk) return;
    float gmax = __uint_as_float(*maxbits);
    float gs = 2688.0f / gmax;                      // (6*448)/max|w|, fp32
    const float4* w4 = (const float4*)w + (size_t)t * 4;
    float4 v0 = w4[0], v1 = w4[1], v2 = w4[2], v3 = w4[3];
    float vv[16];
    vv[0]=v0.x; vv[1]=v0.y; vv[2]=v0.z; vv[3]=v0.w;
    vv[4]=v1.x; vv[5]=v1.y; vv[6]=v1.z; vv[7]=v1.w;
    vv[8]=v2.x; vv[9]=v2.y; vv[10]=v2.z; vv[11]=v2.w;
    vv[12]=v3.x; vv[13]=v3.y; vv[14]=v3.z; vv[15]=v3.w;
    float bmax = 0.0f;
    #pragma unroll
    for (int j = 0; j < 16; ++j) bmax = fmaxf(bmax, fabsf(vv[j]));
    float s_decb = bmax / 6.0f;
    float xs_in  = fminf(s_decb * gs, 448.0f);      // clip (always >= 0)
    float xs_f   = e4m3_rne(xs_in);
    float s_encb = gs / fmaxf(xs_f, 1e-12f);
    float dscale = xs_f / gs;
    bf16x8 o0, o1;
    #pragma unroll
    for (int j = 0; j < 16; ++j) {
        float xsc = vv[j] * s_encb;
        float a = fabsf(xsc);
        float mag = (a <= 0.25f) ? 0.0f
                  : (a <  0.75f) ? 0.5f
                  : (a <= 1.25f) ? 1.0f
                  : (a <  1.75f) ? 1.5f
                  : (a <= 2.5f ) ? 2.0f
                  : (a <  3.5f ) ? 3.0f
                  : (a <= 5.0f ) ? 4.0f : 6.0f;
        float sgn = __builtin_copysignf(1.0f, xsc);
        float val = (sgn * mag) * dscale;
        if (j < 8) o0[j] = (bf16_t)val; else o1[j - 8] = (bf16_t)val;
    }
    *(bf16x8*)(wq + (size_t)t * 16)     = o0;
    *(bf16x8*)(wq + (size_t)t * 16 + 8) = o1;
}

// ---------------- Kernel 3: x fp32 -> bf16 ----------------
__global__ void k_cvt_x(const float* __restrict__ x, bf16_t* __restrict__ xb, long n8) {
    long i = blockIdx.x * (long)blockDim.x + threadIdx.x;
    long stride = (long)gridDim.x * blockDim.x;
    const float4* x4 = (const float4*)x;
    for (; i < n8; i += stride) {
        float4 a = x4[2 * i], b = x4[2 * i + 1];
        bf16x8 o;
        o[0] = (bf16_t)a.x; o[1] = (bf16_t)a.y; o[2] = (bf16_t)a.z; o[3] = (bf16_t)a.w;
        o[4] = (bf16_t)b.x; o[5] = (bf16_t)b.y; o[6] = (bf16_t)b.z; o[7] = (bf16_t)b.w;
        *(bf16x8*)(xb + i * 8) = o;
    }
}

// ---------------- helpers ----------------
__device__ __forceinline__ void BARRIER() {
    asm volatile("" ::: "memory");
    __builtin_amdgcn_s_barrier();
    asm volatile("" ::: "memory");
}

__device__ __forceinline__ void gload16(const bf16_t* g, bf16_t* l) {
    __builtin_amdgcn_global_load_lds(
        (const __attribute__((address_space(1))) unsigned int*)g,
        (__attribute__((address_space(3))) unsigned int*)l,
        16, 0, 0);
}

// swizzle for BK=32 (4 granules of 16B per 64B row): phys granule = row*4 + (g ^ (row&3) ^ ((row>>2)&3))
__device__ __forceinline__ int swzg(int row, int g) {
    return (row << 2) + (g ^ (row & 3) ^ ((row >> 2) & 3));
}

// ---- Kernel 4: 256x256 tile, 8 waves of 128x64, mfma 32x32x16, triple-buffer, vmcnt(4) ----
__global__ __launch_bounds__(NTHREADS, 2) void k_gemm(
        const bf16_t* __restrict__ A,   // [M][K]
        const bf16_t* __restrict__ Bt,  // [N][K]
        const float*  __restrict__ bias,
        float* __restrict__ C, int M, int N, int K) {
    __shared__ __align__(16) bf16_t sA[3][BM * BK];   // 3 x 16 KB
    __shared__ __align__(16) bf16_t sB[3][BN * BK];   // 3 x 16 KB  -> 96 KB total

    // XCD-aware bijective swizzle (gridDim.x % 8 == 0 here)
    int bid = blockIdx.x;
    int cpx = gridDim.x >> 3;
    int swz = (bid & 7) * cpx + (bid >> 3);
    int nbn = N / BN;
    int m0 = (swz / nbn) * BM, n0 = (swz % nbn) * BN;

    int tid  = threadIdx.x;
    int lane = tid & 63;
    int w    = tid >> 6;          // 8 waves: 2 (M) x 4 (N); wave tile 128x64
    int wr   = w >> 2, wc = w & 3;
    int fr   = lane & 31;         // fragment row within 32
    int hi   = lane >> 5;         // k-half granule 0..1

    // staging: A and B each 1024 granules (256 rows x 4), 2 per thread per matrix.
    // inverse swizzle on the GLOBAL source; LDS dest stays linear (rule #21).
    int gof[2], lof[2];
    #pragma unroll
    for (int r = 0; r < 2; ++r) {
        int pf  = r * 512 + tid;
        int row = pf >> 2;
        int lg  = (pf & 3) ^ (row & 3) ^ ((row >> 2) & 3);
        gof[r] = row * K + lg * 8;
        lof[r] = pf * 8;
    }
    const bf16_t* Ab = A  + (size_t)m0 * K;
    const bf16_t* Bb = Bt + (size_t)n0 * K;

#define STAGE(DA, DB, KK) do {                              \
        gload16(Ab + gof[0] + (KK), (DA) + lof[0]);         \
        gload16(Ab + gof[1] + (KK), (DA) + lof[1]);         \
        gload16(Bb + gof[0] + (KK), (DB) + lof[0]);         \
        gload16(Bb + gof[1] + (KK), (DB) + lof[1]);         \
    } while (0)

    // fragment LDS element offsets (swizzled reads); mi/ni stride = 32 rows * 4 gran * 8 elem = 1024
    int aof[2], bof[2];
    #pragma unroll
    for (int kk = 0; kk < 2; ++kk) {
        aof[kk] = swzg(wr * 128 + fr, (kk << 1) + hi) * 8;
        bof[kk] = swzg(wc * 64  + fr, (kk << 1) + hi) * 8;
    }

    f32x16 acc[4][2] = {};

    bf16_t *cA0 = sA[0], *cA1 = sA[1], *cA2 = sA[2];
    bf16_t *cB0 = sB[0], *cB1 = sB[1], *cB2 = sB[2];

    const int NT = K / BK;   // 128

    // prologue: stage t=0 -> buf0, t=1 -> buf1; wait oldest 4 (t=0)
    STAGE(cA0, cB0, 0);
    STAGE(cA1, cB1, BK);
    asm volatile("s_waitcnt vmcnt(4)" ::: "memory");
    BARRIER();

    for (int t = 0; t < NT; ++t) {
        if (t + 2 < NT)
            STAGE(cA2, cB2, (t + 2) * BK);   // 2-tile lead into the idle buffer

        // B fragments for the tile: 2 n-tiles x 2 k-halves
        bf16x8 bf00 = *(const bf16x8*)(cB0 + bof[0]);
        bf16x8 bf01 = *(const bf16x8*)(cB0 + bof[1]);
        bf16x8 bf10 = *(const bf16x8*)(cB0 + 1024 + bof[0]);
        bf16x8 bf11 = *(const bf16x8*)(cB0 + 1024 + bof[1]);
        // A fragments, software-pipelined over mi
        bf16x8 a0 = *(const bf16x8*)(cA0 + aof[0]);
        bf16x8 a1 = *(const bf16x8*)(cA0 + aof[1]);

        __builtin_amdgcn_s_setprio(1);
        #pragma unroll
        for (int mi = 0; mi < 4; ++mi) {
            bf16x8 n0f, n1f;
            if (mi < 3) {
                n0f = *(const bf16x8*)(cA0 + (mi + 1) * 1024 + aof[0]);
                n1f = *(const bf16x8*)(cA0 + (mi + 1) * 1024 + aof[1]);
            }
            acc[mi][0] = __builtin_amdgcn_mfma_f32_32x32x16_bf16(a0, bf00, acc[mi][0], 0, 0, 0);
            acc[mi][0] = __builtin_amdgcn_mfma_f32_32x32x16_bf16(a1, bf01, acc[mi][0], 0, 0, 0);
            acc[mi][1] = __builtin_amdgcn_mfma_f32_32x32x16_bf16(a0, bf10, acc[mi][1], 0, 0, 0);
            acc[mi][1] = __builtin_amdgcn_mfma_f32_32x32x16_bf16(a1, bf11, acc[mi][1], 0, 0, 0);
            if (mi < 3) { a0 = n0f; a1 = n1f; }
        }
        __builtin_amdgcn_s_setprio(0);

        if (t + 2 < NT) {
            asm volatile("s_waitcnt vmcnt(4)" ::: "memory");  // t+1 ready; t+2 stays in flight
        } else {
            asm volatile("s_waitcnt vmcnt(0)" ::: "memory");  // tail
        }
        BARRIER();

        bf16_t* tp;
        tp = cA0; cA0 = cA1; cA1 = cA2; cA2 = tp;
        tp = cB0; cB0 = cB1; cB1 = cB2; cB2 = tp;
    }

    // epilogue: 32x32 C/D mapping: col = lane&31, row = (reg&3) + 8*(reg>>2) + 4*(lane>>5)
    int ccol = lane & 31;
    float bv[2];
    #pragma unroll
    for (int j = 0; j < 2; ++j) bv[j] = bias[n0 + wc * 64 + j * 32 + ccol];
    #pragma unroll
    for (int mi = 0; mi < 4; ++mi) {
        #pragma unroll
        for (int j = 0; j < 2; ++j) {
            size_t cb = (size_t)(m0 + wr * 128 + mi * 32) * N + (n0 + wc * 64 + j * 32 + ccol);
            #pragma unroll
            for (int reg = 0; reg < 16; ++reg) {
                int row = (reg & 3) + 8 * (reg >> 2) + 4 * hi;
                C[cb + (size_t)row * N] = acc[mi][j][reg] + bv[j];
            }
        }
    }
#undef STAGE
}

extern "C" void kernel_launch(void* const* d_in, const int* in_sizes, int n_in,
                              void* d_out, int out_size, void* d_ws, size_t ws_size,
                              hipStream_t stream) {
    const float* x    = (const float*)d_in[0];
    const float* wgt  = (const float*)d_in[1];
    const float* bias = (const float*)d_in[2];
    float* out = (float*)d_out;

    const int N = in_sizes[2];            // 4096 (OUT)
    const int K = in_sizes[1] / N;        // 4096 (IN)
    const int M = in_sizes[0] / K;        // 8192 (B*S)

    unsigned int* maxbits = (unsigned int*)d_ws;
    bf16_t* wq = (bf16_t*)((char*)d_ws + 256);
    bf16_t* xb = (bf16_t*)((char*)d_ws + 256 + (size_t)N * K * sizeof(bf16_t));

    hipMemsetAsync(d_ws, 0, 256, stream);
    k_absmax<<<512, 256, 0, stream>>>(wgt, maxbits, N * K / 4);
    int nblk = N * K / 16;
    k_quantize<<<(nblk + 255) / 256, 256, 0, stream>>>(wgt, wq, maxbits, nblk);
    long n8 = (long)M * K / 8;
    k_cvt_x<<<2048, 256, 0, stream>>>(x, xb, n8);
    dim3 grid((M / BM) * (N / BN));
    k_gemm<<<grid, NTHREADS, 0, stream>>>(xb, wq, bias, out, M, N, K);
}

// Round 6
// 393.611 us; speedup vs baseline: 1.0162x; 1.0162x over previous
//
#include <hip/hip_runtime.h>
#include <hip/hip_bf16.h>
#include <stdint.h>

typedef __bf16 bf16_t;
typedef __bf16 bf16x8 __attribute__((ext_vector_type(8)));
typedef float  f32x16 __attribute__((ext_vector_type(16)));

#define BM 256
#define BN 128
#define BK 32
#define NTHREADS 512

// ---------------- Kernel 1: global absmax of weight ----------------
__global__ void k_absmax(const float* __restrict__ w, unsigned int* __restrict__ out_bits, int n4) {
    int i = blockIdx.x * blockDim.x + threadIdx.x;
    int stride = gridDim.x * blockDim.x;
    const float4* w4 = (const float4*)w;
    float m = 0.0f;
    for (; i < n4; i += stride) {
        float4 v = w4[i];
        m = fmaxf(m, fmaxf(fmaxf(fabsf(v.x), fabsf(v.y)), fmaxf(fabsf(v.z), fabsf(v.w))));
    }
    #pragma unroll
    for (int off = 32; off; off >>= 1)
        m = fmaxf(m, __shfl_xor(m, off));
    if ((threadIdx.x & 63) == 0)
        atomicMax(out_bits, __float_as_uint(m));  // values >= 0: uint order == float order
}

// ---------------- e4m3fn round-to-nearest-even (positive inputs, <= 448) ----------------
__device__ __forceinline__ float e4m3_rne(float v) {
    if (v < 0.015625f) {                 // subnormal range: quantum 2^-9
        return rintf(v * 512.0f) * (1.0f / 512.0f);
    }
    unsigned int u = __float_as_uint(v);
    unsigned int keep = u >> 20;         // sign+exp+3 mantissa bits
    unsigned int r = u & 0xFFFFFu;       // 20 dropped bits
    if (r > 0x80000u || (r == 0x80000u && (keep & 1u))) keep++;
    return __uint_as_float(keep << 20);
}

// ---------------- Kernel 2: NVFP4 fake-quantize weight -> bf16 ----------------
__global__ void k_quantize(const float* __restrict__ w, bf16_t* __restrict__ wq,
                           const unsigned int* __restrict__ maxbits, int nblk) {
    int t = blockIdx.x * blockDim.x + threadIdx.x;
    if (t >= nblk) return;
    float gmax = __uint_as_float(*maxbits);
    float gs = 2688.0f / gmax;                      // (6*448)/max|w|, fp32
    const float4* w4 = (const float4*)w + (size_t)t * 4;
    float4 v0 = w4[0], v1 = w4[1], v2 = w4[2], v3 = w4[3];
    float vv[16];
    vv[0]=v0.x; vv[1]=v0.y; vv[2]=v0.z; vv[3]=v0.w;
    vv[4]=v1.x; vv[5]=v1.y; vv[6]=v1.z; vv[7]=v1.w;
    vv[8]=v2.x; vv[9]=v2.y; vv[10]=v2.z; vv[11]=v2.w;
    vv[12]=v3.x; vv[13]=v3.y; vv[14]=v3.z; vv[15]=v3.w;
    float bmax = 0.0f;
    #pragma unroll
    for (int j = 0; j < 16; ++j) bmax = fmaxf(bmax, fabsf(vv[j]));
    float s_decb = bmax / 6.0f;
    float xs_in  = fminf(s_decb * gs, 448.0f);      // clip (always >= 0)
    float xs_f   = e4m3_rne(xs_in);
    float s_encb = gs / fmaxf(xs_f, 1e-12f);
    float dscale = xs_f / gs;
    bf16x8 o0, o1;
    #pragma unroll
    for (int j = 0; j < 16; ++j) {
        float xsc = vv[j] * s_encb;
        float a = fabsf(xsc);
        float mag = (a <= 0.25f) ? 0.0f
                  : (a <  0.75f) ? 0.5f
                  : (a <= 1.25f) ? 1.0f
                  : (a <  1.75f) ? 1.5f
                  : (a <= 2.5f ) ? 2.0f
                  : (a <  3.5f ) ? 3.0f
                  : (a <= 5.0f ) ? 4.0f : 6.0f;
        float sgn = __builtin_copysignf(1.0f, xsc);
        float val = (sgn * mag) * dscale;
        if (j < 8) o0[j] = (bf16_t)val; else o1[j - 8] = (bf16_t)val;
    }
    *(bf16x8*)(wq + (size_t)t * 16)     = o0;
    *(bf16x8*)(wq + (size_t)t * 16 + 8) = o1;
}

// ---------------- Kernel 3: x fp32 -> bf16 ----------------
__global__ void k_cvt_x(const float* __restrict__ x, bf16_t* __restrict__ xb, long n8) {
    long i = blockIdx.x * (long)blockDim.x + threadIdx.x;
    long stride = (long)gridDim.x * blockDim.x;
    const float4* x4 = (const float4*)x;
    for (; i < n8; i += stride) {
        float4 a = x4[2 * i], b = x4[2 * i + 1];
        bf16x8 o;
        o[0] = (bf16_t)a.x; o[1] = (bf16_t)a.y; o[2] = (bf16_t)a.z; o[3] = (bf16_t)a.w;
        o[4] = (bf16_t)b.x; o[5] = (bf16_t)b.y; o[6] = (bf16_t)b.z; o[7] = (bf16_t)b.w;
        *(bf16x8*)(xb + i * 8) = o;
    }
}

// ---------------- helpers ----------------
__device__ __forceinline__ void BARRIER() {
    asm volatile("" ::: "memory");
    __builtin_amdgcn_s_barrier();
    asm volatile("" ::: "memory");
}

__device__ __forceinline__ void gload16(const bf16_t* g, bf16_t* l) {
    __builtin_amdgcn_global_load_lds(
        (const __attribute__((address_space(1))) unsigned int*)g,
        (__attribute__((address_space(3))) unsigned int*)l,
        16, 0, 0);
}

// swizzle for BK=32 (4 granules of 16B per 64B row): phys granule = row*4 + (g ^ (row&3) ^ ((row>>2)&3))
__device__ __forceinline__ int swzg(int row, int g) {
    return (row << 2) + (g ^ (row & 3) ^ ((row >> 2) & 3));
}

// ---- Kernel 4: 256x128 tile, 8 waves of 64x64 (2x2 of 32x32x16), triple-buffer, 2 blocks/CU ----
__global__ __launch_bounds__(NTHREADS, 4) void k_gemm(
        const bf16_t* __restrict__ A,   // [M][K]
        const bf16_t* __restrict__ Bt,  // [N][K]
        const float*  __restrict__ bias,
        float* __restrict__ C, int M, int N, int K) {
    __shared__ __align__(16) bf16_t sA[3][BM * BK];   // 3 x 16 KB
    __shared__ __align__(16) bf16_t sB[3][BN * BK];   // 3 x 8 KB   -> 72 KB total

    // XCD-aware bijective swizzle (gridDim.x % 8 == 0 here)
    int bid = blockIdx.x;
    int cpx = gridDim.x >> 3;
    int swz = (bid & 7) * cpx + (bid >> 3);
    int nbn = N / BN;
    int m0 = (swz / nbn) * BM, n0 = (swz % nbn) * BN;

    int tid  = threadIdx.x;
    int lane = tid & 63;
    int w    = tid >> 6;          // 8 waves: 4 (M) x 2 (N), each owns 64x64
    int wr   = w >> 1, wc = w & 1;
    int fr   = lane & 31;         // fragment row within 32
    int hi   = lane >> 5;         // k-half-of-16 selector

    // staging: A has 1024 granules (2/thread), B has 512 (1/thread).
    // inverse swizzle on the GLOBAL source; LDS dest stays linear (rule #21).
    int gaof[2], laof[2], gbof, lbof;
    #pragma unroll
    for (int r = 0; r < 2; ++r) {
        int pf  = r * 512 + tid;
        int row = pf >> 2;
        int lg  = (pf & 3) ^ (row & 3) ^ ((row >> 2) & 3);
        gaof[r] = row * K + lg * 8;
        laof[r] = pf * 8;
    }
    {
        int pf  = tid;
        int row = pf >> 2;
        int lg  = (pf & 3) ^ (row & 3) ^ ((row >> 2) & 3);
        gbof = row * K + lg * 8;
        lbof = pf * 8;
    }
    const bf16_t* Ab = A  + (size_t)m0 * K;
    const bf16_t* Bb = Bt + (size_t)n0 * K;

#define STAGE(DA, DB, KK) do {                              \
        gload16(Ab + gaof[0] + (KK), (DA) + laof[0]);       \
        gload16(Ab + gaof[1] + (KK), (DA) + laof[1]);       \
        gload16(Bb + gbof    + (KK), (DB) + lbof);          \
    } while (0)

    // fragment LDS element offsets (swizzled reads), 32x32x16 A/B layout:
    // lane reads row (m or n) = 32-block + (lane&31), k = ks*16 + (lane>>5)*8 .. +8
    // -> granule index ks*2 + hi within the row
    int aof[2][2], bof[2][2];   // [mi or nj][ks]
    #pragma unroll
    for (int mi = 0; mi < 2; ++mi)
        #pragma unroll
        for (int ks = 0; ks < 2; ++ks) {
            aof[mi][ks] = swzg(wr * 64 + mi * 32 + fr, (ks << 1) + hi) * 8;
            bof[mi][ks] = swzg(wc * 64 + mi * 32 + fr, (ks << 1) + hi) * 8;
        }

    f32x16 acc[2][2] = {};

    bf16_t *cA0 = sA[0], *cA1 = sA[1], *cA2 = sA[2];
    bf16_t *cB0 = sB[0], *cB1 = sB[1], *cB2 = sB[2];

    const int NT = K / BK;   // 128

    // prologue: stage t=0 -> buf0, t=1 -> buf1; wait oldest 3 (t=0)
    STAGE(cA0, cB0, 0);
    STAGE(cA1, cB1, BK);
    asm volatile("s_waitcnt vmcnt(3)" ::: "memory");
    BARRIER();

    for (int t = 0; t < NT; ++t) {
        bf16x8 af[2][2], bf[2][2];
        #pragma unroll
        for (int mi = 0; mi < 2; ++mi)
            #pragma unroll
            for (int ks = 0; ks < 2; ++ks) {
                af[mi][ks] = *(const bf16x8*)(cA0 + aof[mi][ks]);
                bf[mi][ks] = *(const bf16x8*)(cB0 + bof[mi][ks]);
            }

        if (t + 2 < NT)
            STAGE(cA2, cB2, (t + 2) * BK);   // 2-tile lead into the idle buffer

        __builtin_amdgcn_s_setprio(1);
        #pragma unroll
        for (int mi = 0; mi < 2; ++mi)
            #pragma unroll
            for (int nj = 0; nj < 2; ++nj) {
                acc[mi][nj] = __builtin_amdgcn_mfma_f32_32x32x16_bf16(af[mi][0], bf[nj][0], acc[mi][nj], 0, 0, 0);
                acc[mi][nj] = __builtin_amdgcn_mfma_f32_32x32x16_bf16(af[mi][1], bf[nj][1], acc[mi][nj], 0, 0, 0);
            }
        __builtin_amdgcn_s_setprio(0);

        if (t + 2 < NT) {
            asm volatile("s_waitcnt vmcnt(3)" ::: "memory");  // t+1 ready; t+2 stays in flight
        } else {
            asm volatile("s_waitcnt vmcnt(0)" ::: "memory");  // tail (last 2 tiles only)
        }
        BARRIER();

        bf16_t* tp;
        tp = cA0; cA0 = cA1; cA1 = cA2; cA2 = tp;
        tp = cB0; cB0 = cB1; cB1 = cB2; cB2 = tp;
    }

    // epilogue: 32x32 C/D mapping: col = lane&31, row = (reg&3) + 8*(reg>>2) + 4*(lane>>5)
    int ccol = lane & 31;
    float bv[2];
    #pragma unroll
    for (int nj = 0; nj < 2; ++nj) bv[nj] = bias[n0 + wc * 64 + nj * 32 + ccol];
    #pragma unroll
    for (int mi = 0; mi < 2; ++mi) {
        #pragma unroll
        for (int nj = 0; nj < 2; ++nj) {
            size_t cb = (size_t)(m0 + wr * 64 + mi * 32) * N + (n0 + wc * 64 + nj * 32 + ccol);
            #pragma unroll
            for (int reg = 0; reg < 16; ++reg) {
                int row = (reg & 3) + 8 * (reg >> 2) + 4 * hi;
                C[cb + (size_t)row * N] = acc[mi][nj][reg] + bv[nj];
            }
        }
    }
#undef STAGE
}

extern "C" void kernel_launch(void* const* d_in, const int* in_sizes, int n_in,
                              void* d_out, int out_size, void* d_ws, size_t ws_size,
                              hipStream_t stream) {
    const float* x    = (const float*)d_in[0];
    const float* wgt  = (const float*)d_in[1];
    const float* bias = (const float*)d_in[2];
    float* out = (float*)d_out;

    const int N = in_sizes[2];            // 4096 (OUT)
    const int K = in_sizes[1] / N;        // 4096 (IN)
    const int M = in_sizes[0] / K;        // 8192 (B*S)

    unsigned int* maxbits = (unsigned int*)d_ws;
    bf16_t* wq = (bf16_t*)((char*)d_ws + 256);
    bf16_t* xb = (bf16_t*)((char*)d_ws + 256 + (size_t)N * K * sizeof(bf16_t));

    hipMemsetAsync(d_ws, 0, 256, stream);
    k_absmax<<<512, 256, 0, stream>>>(wgt, maxbits, N * K / 4);
    int nblk = N * K / 16;
    k_quantize<<<(nblk + 255) / 256, 256, 0, stream>>>(wgt, wq, maxbits, nblk);
    long n8 = (long)M * K / 8;
    k_cvt_x<<<2048, 256, 0, stream>>>(x, xb, n8);
    dim3 grid((M / BM) * (N / BN));
    k_gemm<<<grid, NTHREADS, 0, stream>>>(xb, wq, bias, out, M, N, K);
}

// Round 7
// 336.013 us; speedup vs baseline: 1.1904x; 1.1714x over previous
//
#include <hip/hip_runtime.h>
#include <hip/hip_bf16.h>
#include <stdint.h>

typedef __bf16 bf16_t;
typedef __bf16 bf16x8 __attribute__((ext_vector_type(8)));
typedef float  f32x4  __attribute__((ext_vector_type(4)));

#define BM 256
#define BN 256
#define BK 64
#define NTHREADS 512

// ---------------- Kernel 1: global absmax of weight ----------------
__global__ void k_absmax(const float* __restrict__ w, unsigned int* __restrict__ out_bits, int n4) {
    int i = blockIdx.x * blockDim.x + threadIdx.x;
    int stride = gridDim.x * blockDim.x;
    const float4* w4 = (const float4*)w;
    float m = 0.0f;
    for (; i < n4; i += stride) {
        float4 v = w4[i];
        m = fmaxf(m, fmaxf(fmaxf(fabsf(v.x), fabsf(v.y)), fmaxf(fabsf(v.z), fabsf(v.w))));
    }
    #pragma unroll
    for (int off = 32; off; off >>= 1)
        m = fmaxf(m, __shfl_xor(m, off));
    if ((threadIdx.x & 63) == 0)
        atomicMax(out_bits, __float_as_uint(m));  // values >= 0: uint order == float order
}

// ---------------- e4m3fn round-to-nearest-even (positive inputs, <= 448) ----------------
__device__ __forceinline__ float e4m3_rne(float v) {
    if (v < 0.015625f) {                 // subnormal range: quantum 2^-9
        return rintf(v * 512.0f) * (1.0f / 512.0f);
    }
    unsigned int u = __float_as_uint(v);
    unsigned int keep = u >> 20;         // sign+exp+3 mantissa bits
    unsigned int r = u & 0xFFFFFu;       // 20 dropped bits
    if (r > 0x80000u || (r == 0x80000u && (keep & 1u))) keep++;
    return __uint_as_float(keep << 20);
}

// ---------------- Kernel 2: NVFP4 fake-quantize weight -> bf16 ----------------
__global__ void k_quantize(const float* __restrict__ w, bf16_t* __restrict__ wq,
                           const unsigned int* __restrict__ maxbits, int nblk) {
    int t = blockIdx.x * blockDim.x + threadIdx.x;
    if (t >= nblk) return;
    float gmax = __uint_as_float(*maxbits);
    float gs = 2688.0f / gmax;                      // (6*448)/max|w|, fp32
    const float4* w4 = (const float4*)w + (size_t)t * 4;
    float4 v0 = w4[0], v1 = w4[1], v2 = w4[2], v3 = w4[3];
    float vv[16];
    vv[0]=v0.x; vv[1]=v0.y; vv[2]=v0.z; vv[3]=v0.w;
    vv[4]=v1.x; vv[5]=v1.y; vv[6]=v1.z; vv[7]=v1.w;
    vv[8]=v2.x; vv[9]=v2.y; vv[10]=v2.z; vv[11]=v2.w;
    vv[12]=v3.x; vv[13]=v3.y; vv[14]=v3.z; vv[15]=v3.w;
    float bmax = 0.0f;
    #pragma unroll
    for (int j = 0; j < 16; ++j) bmax = fmaxf(bmax, fabsf(vv[j]));
    float s_decb = bmax / 6.0f;
    float xs_in  = fminf(s_decb * gs, 448.0f);      // clip (always >= 0)
    float xs_f   = e4m3_rne(xs_in);
    float s_encb = gs / fmaxf(xs_f, 1e-12f);
    float dscale = xs_f / gs;
    bf16x8 o0, o1;
    #pragma unroll
    for (int j = 0; j < 16; ++j) {
        float xsc = vv[j] * s_encb;
        float a = fabsf(xsc);
        float mag = (a <= 0.25f) ? 0.0f
                  : (a <  0.75f) ? 0.5f
                  : (a <= 1.25f) ? 1.0f
                  : (a <  1.75f) ? 1.5f
                  : (a <= 2.5f ) ? 2.0f
                  : (a <  3.5f ) ? 3.0f
                  : (a <= 5.0f ) ? 4.0f : 6.0f;
        float sgn = __builtin_copysignf(1.0f, xsc);
        float val = (sgn * mag) * dscale;
        if (j < 8) o0[j] = (bf16_t)val; else o1[j - 8] = (bf16_t)val;
    }
    *(bf16x8*)(wq + (size_t)t * 16)     = o0;
    *(bf16x8*)(wq + (size_t)t * 16 + 8) = o1;
}

// ---------------- Kernel 3: x fp32 -> bf16 ----------------
__global__ void k_cvt_x(const float* __restrict__ x, bf16_t* __restrict__ xb, long n8) {
    long i = blockIdx.x * (long)blockDim.x + threadIdx.x;
    long stride = (long)gridDim.x * blockDim.x;
    const float4* x4 = (const float4*)x;
    for (; i < n8; i += stride) {
        float4 a = x4[2 * i], b = x4[2 * i + 1];
        bf16x8 o;
        o[0] = (bf16_t)a.x; o[1] = (bf16_t)a.y; o[2] = (bf16_t)a.z; o[3] = (bf16_t)a.w;
        o[4] = (bf16_t)b.x; o[5] = (bf16_t)b.y; o[6] = (bf16_t)b.z; o[7] = (bf16_t)b.w;
        *(bf16x8*)(xb + i * 8) = o;
    }
}

// ---------------- helpers ----------------
__device__ __forceinline__ void BARRIER() {
    asm volatile("" ::: "memory");
    __builtin_amdgcn_s_barrier();
    asm volatile("" ::: "memory");
}

__device__ __forceinline__ void gload16(const bf16_t* g, bf16_t* l) {
    __builtin_amdgcn_global_load_lds(
        (const __attribute__((address_space(1))) unsigned int*)g,
        (__attribute__((address_space(3))) unsigned int*)l,
        16, 0, 0);
}

// ---- Kernel 4: 256x256, BK=64, m201 8-phase schedule, half-tile staging, vmcnt(6) ----
// LDS tile layout: row r (0..255) holds 8 granules of 16B; logical granule g stored at
// physical slot g ^ (r & 7).  Staged via inverse-swizzled GLOBAL source (rule #21).
__global__ __launch_bounds__(NTHREADS, 2) void k_gemm(
        const bf16_t* __restrict__ A,   // [M][K]
        const bf16_t* __restrict__ Bt,  // [N][K]
        const float*  __restrict__ bias,
        float* __restrict__ C, int M, int N, int K) {
    __shared__ __align__(16) bf16_t sA[2][BM * BK];   // 2 x 32 KB
    __shared__ __align__(16) bf16_t sB[2][BN * BK];   // 2 x 32 KB  -> 128 KB

    // XCD-aware bijective swizzle (gridDim.x % 8 == 0 here)
    int bid = blockIdx.x;
    int cpx = gridDim.x >> 3;
    int swz = (bid & 7) * cpx + (bid >> 3);
    int nbn = N / BN;
    int m0 = (swz / nbn) * BM, n0 = (swz % nbn) * BN;

    int tid  = threadIdx.x;
    int lane = tid & 63;
    int w    = tid >> 6;          // 8 waves: 2 (M) x 4 (N); wave tile 128x64
    int wr   = w >> 2, wc = w & 3;
    int fr15 = lane & 15;
    int kg   = lane >> 4;         // k-granule within 32-k slot

    // ---- staging precompute: half-tile h covers rows {h*64..h*64+63} U {128+h*64..}
    // (l=0 -> low 128-block, l=1 -> high block). 2 gloads/thread per half-tile.
    int rowin = (tid >> 3) & 63;
    int pg    = tid & 7;
    int gsw   = pg ^ (rowin & 7);              // logical granule staged into phys slot pg
    int gstg[2], lstg[2];
    #pragma unroll
    for (int l = 0; l < 2; ++l) {
        gstg[l] = (l * 128 + rowin) * K + gsw * 8;   // + h*64*K + kt at call
        lstg[l] = (l * 128 + rowin) * 64 + pg * 8;   // + h*4096 at call
    }
    const bf16_t* Ab = A  + (size_t)m0 * K;
    const bf16_t* Bb = Bt + (size_t)n0 * K;

#define STG(SX, Xb, BUF, H, KT) do {                                              \
        gload16(Xb + (H) * 64 * K + gstg[0] + (KT), &SX[BUF][(H) * 4096 + lstg[0]]); \
        gload16(Xb + (H) * 64 * K + gstg[1] + (KT), &SX[BUF][(H) * 4096 + lstg[1]]); \
    } while (0)

    // ---- read-offset precompute: row = R0 + q*32 + i*16 (multiples of 8 don't change
    // row&7 = fr15&7), so phys granule = (ks*4+kg) ^ (fr15&7) is q/i-invariant ->
    // 2 base offsets + compile-time immediates.
    int f01 = fr15 & 3, f2 = (fr15 >> 2) & 1;
    int pgr0 = 4 * (0 ^ f2) + (kg ^ f01);
    int pgr1 = 4 * (1 ^ f2) + (kg ^ f01);
    int baseA0 = (wr * 128 + fr15) * 64 + pgr0 * 8;
    int baseA1 = (wr * 128 + fr15) * 64 + pgr1 * 8;
    int baseB0 = (wc * 64  + fr15) * 64 + pgr0 * 8;
    int baseB1 = (wc * 64  + fr15) * 64 + pgr1 * 8;

    f32x4 acc[8][4] = {};
    bf16x8 bfr[4][2];

    const int NT = K / BK;        // 64 tiles
    const int ITERS = NT / 2;     // 32

    // ---- prologue: B0(2h), A0(2h), B1(2h), A1(h0)  = 14 loads; vmcnt(6) -> tile0 landed
    STG(sB, Bb, 0, 0, 0);  STG(sB, Bb, 0, 1, 0);
    STG(sA, Ab, 0, 0, 0);  STG(sA, Ab, 0, 1, 0);
    STG(sB, Bb, 1, 0, BK); STG(sB, Bb, 1, 1, BK);
    STG(sA, Ab, 1, 0, BK);
    asm volatile("s_waitcnt vmcnt(6)" ::: "memory");
    BARRIER();

#define RDA(PA, Q, A0K0, A0K1, A1K0, A1K1)                                \
    bf16x8 A0K0 = *(const bf16x8*)((PA) + baseA0 + (Q) * 2048);            \
    bf16x8 A0K1 = *(const bf16x8*)((PA) + baseA1 + (Q) * 2048);            \
    bf16x8 A1K0 = *(const bf16x8*)((PA) + baseA0 + (Q) * 2048 + 1024);     \
    bf16x8 A1K1 = *(const bf16x8*)((PA) + baseA1 + (Q) * 2048 + 1024);

#define RDB(PB) do {                                                       \
        _Pragma("unroll")                                                  \
        for (int j = 0; j < 4; ++j) {                                      \
            bfr[j][0] = *(const bf16x8*)((PB) + baseB0 + j * 1024);        \
            bfr[j][1] = *(const bf16x8*)((PB) + baseB1 + j * 1024);        \
        }                                                                  \
    } while (0)

#define MF16(Q, A0K0, A0K1, A1K0, A1K1) do {                                                       \
        __builtin_amdgcn_s_setprio(1);                                                             \
        _Pragma("unroll")                                                                          \
        for (int j = 0; j < 4; ++j) {                                                              \
            acc[(Q)*2+0][j] = __builtin_amdgcn_mfma_f32_16x16x32_bf16(A0K0, bfr[j][0], acc[(Q)*2+0][j], 0, 0, 0); \
            acc[(Q)*2+0][j] = __builtin_amdgcn_mfma_f32_16x16x32_bf16(A0K1, bfr[j][1], acc[(Q)*2+0][j], 0, 0, 0); \
            acc[(Q)*2+1][j] = __builtin_amdgcn_mfma_f32_16x16x32_bf16(A1K0, bfr[j][0], acc[(Q)*2+1][j], 0, 0, 0); \
            acc[(Q)*2+1][j] = __builtin_amdgcn_mfma_f32_16x16x32_bf16(A1K1, bfr[j][1], acc[(Q)*2+1][j], 0, 0, 0); \
        }                                                                                          \
        __builtin_amdgcn_s_setprio(0);                                                             \
    } while (0)

#define LGKM0() asm volatile("s_waitcnt lgkmcnt(0)" ::: "memory")
#define LGKM8() asm volatile("s_waitcnt lgkmcnt(8)" ::: "memory")

    for (int it = 0; it < ITERS; ++it) {
        const bool nl = (it + 1 < ITERS);
        const int ktP = (2 * it + 1) * BK;   // pending A-h1 of current buf1 tile
        const int kt2 = (2 * it + 2) * BK;   // tile -> buf0
        const int kt3 = (2 * it + 3) * BK;   // tile -> buf1

        // PH0: Q0 from buf0; read B(buf0)+A-q0 (12 reads); stage A(t+1)h1 -> buf1
        {
            RDA(sA[0], 0, a00, a01, a10, a11);
            RDB(sB[0]);
            STG(sA, Ab, 1, 1, ktP);
            LGKM8();
            BARRIER(); LGKM0();
            MF16(0, a00, a01, a10, a11);
            BARRIER();
        }
        // PH1: Q1 buf0; stage B(t+2)h0 -> buf0
        {
            RDA(sA[0], 1, a00, a01, a10, a11);
            if (nl) STG(sB, Bb, 0, 0, kt2);
            BARRIER(); LGKM0();
            MF16(1, a00, a01, a10, a11);
            BARRIER();
        }
        // PH2: Q2 buf0; stage B(t+2)h1 -> buf0
        {
            RDA(sA[0], 2, a00, a01, a10, a11);
            if (nl) STG(sB, Bb, 0, 1, kt2);
            BARRIER(); LGKM0();
            MF16(2, a00, a01, a10, a11);
            BARRIER();
        }
        // PH3: Q3 buf0; stage A(t+2)h0 -> buf0; tail vmcnt publishes tile t+1
        {
            RDA(sA[0], 3, a00, a01, a10, a11);
            if (nl) STG(sA, Ab, 0, 0, kt2);
            BARRIER(); LGKM0();
            MF16(3, a00, a01, a10, a11);
            if (nl) { asm volatile("s_waitcnt vmcnt(6)" ::: "memory"); }
            else    { asm volatile("s_waitcnt vmcnt(0)" ::: "memory"); }
            BARRIER();
        }
        // PH4: Q0 from buf1; read B(buf1)+A-q0 (12 reads); stage A(t+2)h1 -> buf0
        {
            RDA(sA[1], 0, a00, a01, a10, a11);
            RDB(sB[1]);
            if (nl) STG(sA, Ab, 0, 1, kt2);
            LGKM8();
            BARRIER(); LGKM0();
            MF16(0, a00, a01, a10, a11);
            BARRIER();
        }
        // PH5: Q1 buf1; stage B(t+3)h0 -> buf1
        {
            RDA(sA[1], 1, a00, a01, a10, a11);
            if (nl) STG(sB, Bb, 1, 0, kt3);
            BARRIER(); LGKM0();
            MF16(1, a00, a01, a10, a11);
            BARRIER();
        }
        // PH6: Q2 buf1; stage B(t+3)h1 -> buf1
        {
            RDA(sA[1], 2, a00, a01, a10, a11);
            if (nl) STG(sB, Bb, 1, 1, kt3);
            BARRIER(); LGKM0();
            MF16(2, a00, a01, a10, a11);
            BARRIER();
        }
        // PH7: Q3 buf1; stage A(t+3)h0 -> buf1; tail vmcnt publishes tile t+2
        {
            RDA(sA[1], 3, a00, a01, a10, a11);
            if (nl) STG(sA, Ab, 1, 0, kt3);
            BARRIER(); LGKM0();
            MF16(3, a00, a01, a10, a11);
            if (nl) { asm volatile("s_waitcnt vmcnt(6)" ::: "memory"); }
            BARRIER();
        }
    }
    asm volatile("s_waitcnt vmcnt(0)" ::: "memory");  // drain before epilogue

    // epilogue: C/D mapping col = lane&15, row = (lane>>4)*4 + reg
    int crow = (lane >> 4) * 4;
    int ccol = lane & 15;
    float bv[4];
    #pragma unroll
    for (int j = 0; j < 4; ++j) bv[j] = bias[n0 + wc * 64 + j * 16 + ccol];
    #pragma unroll
    for (int i = 0; i < 8; ++i) {
        size_t mrow = (size_t)(m0 + wr * 128 + i * 16 + crow);
        #pragma unroll
        for (int j = 0; j < 4; ++j) {
            float* cp = C + mrow * N + (n0 + wc * 64 + j * 16 + ccol);
            #pragma unroll
            for (int r = 0; r < 4; ++r)
                cp[(size_t)r * N] = acc[i][j][r] + bv[j];
        }
    }
#undef STG
#undef RDA
#undef RDB
#undef MF16
#undef LGKM0
#undef LGKM8
}

extern "C" void kernel_launch(void* const* d_in, const int* in_sizes, int n_in,
                              void* d_out, int out_size, void* d_ws, size_t ws_size,
                              hipStream_t stream) {
    const float* x    = (const float*)d_in[0];
    const float* wgt  = (const float*)d_in[1];
    const float* bias = (const float*)d_in[2];
    float* out = (float*)d_out;

    const int N = in_sizes[2];            // 4096 (OUT)
    const int K = in_sizes[1] / N;        // 4096 (IN)
    const int M = in_sizes[0] / K;        // 8192 (B*S)

    unsigned int* maxbits = (unsigned int*)d_ws;
    bf16_t* wq = (bf16_t*)((char*)d_ws + 256);
    bf16_t* xb = (bf16_t*)((char*)d_ws + 256 + (size_t)N * K * sizeof(bf16_t));

    hipMemsetAsync(d_ws, 0, 256, stream);
    k_absmax<<<512, 256, 0, stream>>>(wgt, maxbits, N * K / 4);
    int nblk = N * K / 16;
    k_quantize<<<(nblk + 255) / 256, 256, 0, stream>>>(wgt, wq, maxbits, nblk);
    long n8 = (long)M * K / 8;
    k_cvt_x<<<2048, 256, 0, stream>>>(x, xb, n8);
    dim3 grid((M / BM) * (N / BN));
    k_gemm<<<grid, NTHREADS, 0, stream>>>(xb, wq, bias, out, M, N, K);
}